// Round 3
// baseline (124.820 us; speedup 1.0000x reference)
//
#include <hip/hip_runtime.h>
#include <hip/hip_bf16.h>

// Nav_64939905516231 (VIN value iteration), MI355X gfx950.
// B=64,H=W=64,dim_h=150,n_hat=8,n_act=4,K=10. fp32 in/out, maze int32.
// Collapses: r = conv5x5(m,W_eff)+b_eff (150ch folded); q_t = q0 + conv5x5(v,w).
// R25 = R24 + writeback fix (m6,m7 went to col 10+p8 instead of 8+p8 -> race
// with neighbor lane + stale cols; absmax 7e-2). Structure: occupancy 2->4
// waves/SIMD. Per-lane channels 4->2 (weights 100->50 regs, total ~110 <= 128),
// lane = (cq = lane>>4 channel-pair, roff = (lane>>3)&1 row, p8 = (lane&7)*8).
// Tap reads are 4-way same-address broadcast across cq groups (free). 8-ch max
// via 2 shfl_xor rounds (16,32). Block = 1024 thr = 16 waves,
// __launch_bounds__(1024,4) -> 1 blk/CU, 4 waves/SIMD, no extra halo compute.
// q0g re-blocked to [b][r][chpair][px] v2f (lane q0 = one 64B contiguous read).
// ~44us ws-poison fill + ~18us dispatch are harness-fixed.

#define NHAT 8
#define DIMH 150

typedef float v2f __attribute__((ext_vector_type(2)));

// ------- rq: prep (parallel) + r = table-conv(maze) + q0 -------
// q0 layout: q0g[(((b*64+gy)*4 + j)*64 + gx)*2] v2f = ch pair (2j,2j+1).
__global__ __launch_bounds__(512) void rq_kernel(
    const int* __restrict__ maze, const float* __restrict__ emb,
    const float* __restrict__ encode_w, const float* __restrict__ encode_b,
    const float* __restrict__ r_w, const float* __restrict__ q_w,
    float* __restrict__ q0g) {
  __shared__ float wpart[5][50];
  __shared__ float bpart[152];
  __shared__ float weff[2][25];
  __shared__ float Ts[4][25];
  __shared__ float bsh;
  __shared__ v2f qw2[25][4];
  __shared__ unsigned char mzt[24][68];
  __shared__ float rt[20][68];

  int tid = threadIdx.x;
  int b = blockIdx.y, A0 = blockIdx.x * 16;

  // P0: weight stage + W_eff partials + maze tile
  if (tid < 100) {
    int k = tid >> 2, j = tid & 3;
    qw2[k][j] = (v2f){q_w[(2 * j) * 25 + k], q_w[(2 * j + 1) * 25 + k]};
  }
  if (tid >= 256 && tid < 506) {
    int t2 = tid - 256;
    int chunk = t2 / 50, ik = t2 % 50;
    int i = ik / 25, k = ik % 25;
    int c0 = chunk * 30;
    float s = 0.f;
    for (int c = c0; c < c0 + 30; ++c)
      s += r_w[c] * encode_w[c * 50 + i * 25 + k];
    wpart[chunk][ik] = s;
  }
  if (tid >= 100 && tid < 250) {
    int c = tid - 100;
    bpart[c] = r_w[c] * encode_b[c];
  }
  for (int i = tid; i < 24 * 68; i += 512) {
    int mr = i / 68, mc = i % 68;
    int gy = A0 - 4 + mr, gx = mc - 2;
    unsigned char v = 3;
    if (gy >= 0 && gy < 64 && gx >= 0 && gx < 64)
      v = (unsigned char)maze[(b * 64 + gy) * 64 + gx];
    mzt[mr][mc] = v;
  }
  __syncthreads();
  // P1: reduce
  if (tid < 50) {
    float s = 0.f;
#pragma unroll
    for (int ch = 0; ch < 5; ++ch) s += wpart[ch][tid];
    weff[tid / 25][tid % 25] = s;
  }
  if (tid == 50) {
    float s = 0.f;
    for (int c = 0; c < 150; ++c) s += bpart[c];
    bsh = s;
  }
  __syncthreads();
  // P2: T table
  if (tid < 100) {
    int val = tid / 25, k = tid % 25;
    float t = 0.f;
    if (val < 3) t = weff[0][k] * emb[val * 2] + weff[1][k] * emb[val * 2 + 1];
    Ts[val][k] = t;  // row 3 == 0 (padding sentinel)
  }
  __syncthreads();
  // P3: r tile rows [A0-2, A0+18)
  for (int i = tid; i < 20 * 68; i += 512) {
    int rr = i / 68, cc = i % 68;
    int gy = A0 - 2 + rr, gx = cc - 2;
    float v = 0.f;
    if (gy >= 0 && gy < 64 && gx >= 0 && gx < 64) {
      v = bsh;
#pragma unroll
      for (int ky = 0; ky < 5; ++ky)
#pragma unroll
        for (int kx = 0; kx < 5; ++kx)
          v += Ts[mzt[rr + ky][cc - 2 + kx]][ky * 5 + kx];
    }
    rt[rr][cc] = v;
  }
  __syncthreads();
  // P4: q0 on owned 16 rows -> [b][gy][chpair][gx] v2f
  for (int i = tid; i < 16 * 64; i += 512) {
    int ly = i >> 6, gx = i & 63;
    int gy = A0 + ly;
    v2f acc[4];
#pragma unroll
    for (int j = 0; j < 4; ++j) acc[j] = (v2f){0.f, 0.f};
#pragma unroll
    for (int ky = 0; ky < 5; ++ky)
#pragma unroll
      for (int kx = 0; kx < 5; ++kx) {
        int k = ky * 5 + kx;
        float vv = rt[ly + ky][gx + kx];
        v2f vv2 = (v2f){vv, vv};
#pragma unroll
        for (int j = 0; j < 4; ++j) acc[j] += qw2[k][j] * vv2;
      }
#pragma unroll
    for (int j = 0; j < 4; ++j)
      *(v2f*)&q0g[(((size_t)(b * 64 + gy) * 4 + j) * 64 + gx) * 2] = acc[j];
  }
}

// =============== vi: 10 fused VI steps + projection =================
// Block (1024 thr = 16 waves) owns rows [a0, a0+16); grid 256 (1 blk/CU).
// Lane: cq = lane>>4 (channel pair), roff = (lane>>3)&1 (row in pair),
// p8 = (lane&7)*8 (8-px group). All 4 cq groups read the SAME vbuf taps
// (4-way LDS broadcast, free). 8-ch max via shfl_xor(16) + shfl_xor(32);
// cq==0 lanes write the combined row at cols 2+p8..9+p8. 1 barrier/step.
__global__ __launch_bounds__(1024, 4) void vi_kernel(
    const float* __restrict__ q0g, const float* __restrict__ w,
    const float* __restrict__ fc_w, float* __restrict__ out) {
  __shared__ __align__(16) float vbuf[2][60][68];  // 32.6 KB
  __shared__ v2f wl2[25][4];

  int tid = threadIdx.x;
  int b = blockIdx.y, a0 = blockIdx.x * 16;
  int wave = tid >> 6, lane = tid & 63;
  int cq = lane >> 4;          // channel pair 0..3
  int roff = (lane >> 3) & 1;  // row within pair
  int p8 = (lane & 7) * 8;     // px group start

  if (tid < 100) {
    int k = tid >> 2, j = tid & 3;
    wl2[k][j] = (v2f){w[(2 * j) * 25 + k], w[(2 * j + 1) * 25 + k]};
  }
  for (int i = tid; i < 2 * 60 * 68; i += 1024) ((float*)vbuf)[i] = 0.f;
  __syncthreads();

  // this lane's 2 channels -> 25 v2f = 50 regs
  v2f wr[25];
#pragma unroll
  for (int k = 0; k < 25; ++k) wr[k] = wl2[k][cq];

  const float* q0b = q0g + (size_t)b * 64 * 4 * 64 * 2;
  int cur = 0;

  // v0 = max_c q0 on [a0-20, a0+36): full 8ch per lane, waves stride 16 rows
  {
    int s = max(0, a0 - 20), e = min(64, a0 + 36);
    int gx = lane;
    for (int r = s + wave; r < e; r += 16) {
      v2f a0v = *(const v2f*)&q0b[(((size_t)r * 4 + 0) * 64 + gx) * 2];
      v2f a1v = *(const v2f*)&q0b[(((size_t)r * 4 + 1) * 64 + gx) * 2];
      v2f a2v = *(const v2f*)&q0b[(((size_t)r * 4 + 2) * 64 + gx) * 2];
      v2f a3v = *(const v2f*)&q0b[(((size_t)r * 4 + 3) * 64 + gx) * 2];
      float m = fmaxf(fmaxf(fmaxf(a0v.x, a0v.y), fmaxf(a1v.x, a1v.y)),
                      fmaxf(fmaxf(a2v.x, a2v.y), fmaxf(a3v.x, a3v.y)));
      vbuf[0][r - a0 + 22][gx + 2] = m;
    }
  }
  __syncthreads();

  for (int t = 1; t <= 9; ++t) {
    int hh = 2 * (10 - t);
    int s = max(0, a0 - hh), e = min(64, a0 + 16 + hh);
    for (int rb = s + 2 * wave; rb < e; rb += 32) {
      int r = rb + roff;
      if (r < e) {  // shfl partners (xor 16/32) share r -> safe
        int lr = r - a0 + 22;
        const float4* qp =
            (const float4*)&q0b[(((size_t)r * 4 + cq) * 64 + p8) * 2];
        float4 qv0 = qp[0], qv1 = qp[1], qv2 = qp[2], qv3 = qp[3];
        v2f aA[8];
#pragma unroll
        for (int j = 0; j < 8; ++j) aA[j] = (v2f){0.f, 0.f};
#pragma unroll
        for (int jj = 0; jj < 5; ++jj) {
          const float* row = &vbuf[cur][lr - 2 + jj][p8];
          float4 fa = *(const float4*)row;
          float4 fb = *(const float4*)(row + 4);
          float4 fc = *(const float4*)(row + 8);
          float f[12] = {fa.x, fa.y, fa.z, fa.w, fb.x, fb.y,
                         fb.z, fb.w, fc.x, fc.y, fc.z, fc.w};
#pragma unroll
          for (int kx = 0; kx < 5; ++kx) {
            v2f wk = wr[jj * 5 + kx];
#pragma unroll
            for (int j = 0; j < 8; ++j) {
              v2f vv2 = (v2f){f[j + kx], f[j + kx]};
              aA[j] += wk * vv2;
            }
          }
        }
        // q0 added after the tap chain: L2 latency hides under FMAs
        aA[0] += (v2f){qv0.x, qv0.y}; aA[1] += (v2f){qv0.z, qv0.w};
        aA[2] += (v2f){qv1.x, qv1.y}; aA[3] += (v2f){qv1.z, qv1.w};
        aA[4] += (v2f){qv2.x, qv2.y}; aA[5] += (v2f){qv2.z, qv2.w};
        aA[6] += (v2f){qv3.x, qv3.y}; aA[7] += (v2f){qv3.z, qv3.w};
        float m0 = fmaxf(aA[0].x, aA[0].y), m1 = fmaxf(aA[1].x, aA[1].y);
        float m2 = fmaxf(aA[2].x, aA[2].y), m3 = fmaxf(aA[3].x, aA[3].y);
        float m4 = fmaxf(aA[4].x, aA[4].y), m5 = fmaxf(aA[5].x, aA[5].y);
        float m6 = fmaxf(aA[6].x, aA[6].y), m7 = fmaxf(aA[7].x, aA[7].y);
        // combine the 4 channel pairs in-register (butterfly over cq)
        m0 = fmaxf(m0, __shfl_xor(m0, 16)); m0 = fmaxf(m0, __shfl_xor(m0, 32));
        m1 = fmaxf(m1, __shfl_xor(m1, 16)); m1 = fmaxf(m1, __shfl_xor(m1, 32));
        m2 = fmaxf(m2, __shfl_xor(m2, 16)); m2 = fmaxf(m2, __shfl_xor(m2, 32));
        m3 = fmaxf(m3, __shfl_xor(m3, 16)); m3 = fmaxf(m3, __shfl_xor(m3, 32));
        m4 = fmaxf(m4, __shfl_xor(m4, 16)); m4 = fmaxf(m4, __shfl_xor(m4, 32));
        m5 = fmaxf(m5, __shfl_xor(m5, 16)); m5 = fmaxf(m5, __shfl_xor(m5, 32));
        m6 = fmaxf(m6, __shfl_xor(m6, 16)); m6 = fmaxf(m6, __shfl_xor(m6, 32));
        m7 = fmaxf(m7, __shfl_xor(m7, 16)); m7 = fmaxf(m7, __shfl_xor(m7, 32));
        if (cq == 0) {
          // pixels p8+0..p8+7 -> cols 2+p8 .. 9+p8
          *(v2f*)&vbuf[cur ^ 1][lr][2 + p8] = (v2f){m0, m1};
          *(float4*)&vbuf[cur ^ 1][lr][4 + p8] = make_float4(m2, m3, m4, m5);
          *(v2f*)&vbuf[cur ^ 1][lr][8 + p8] = (v2f){m6, m7};
        }
      }
    }
    __syncthreads();
    cur ^= 1;
  }

  // final step t=10 + projection: rows [a0, a0+16); waves 0-7 (2 rows each)
  if (wave < 8) {
    int r = a0 + 2 * wave + roff;
    int lr = r - a0 + 22;
    const float4* qp =
        (const float4*)&q0b[(((size_t)r * 4 + cq) * 64 + p8) * 2];
    float4 qv0 = qp[0], qv1 = qp[1], qv2 = qp[2], qv3 = qp[3];
    v2f aA[8];
#pragma unroll
    for (int j = 0; j < 8; ++j) aA[j] = (v2f){0.f, 0.f};
#pragma unroll
    for (int jj = 0; jj < 5; ++jj) {
      const float* row = &vbuf[cur][lr - 2 + jj][p8];
      float4 fa = *(const float4*)row;
      float4 fb = *(const float4*)(row + 4);
      float4 fc = *(const float4*)(row + 8);
      float f[12] = {fa.x, fa.y, fa.z, fa.w, fb.x, fb.y,
                     fb.z, fb.w, fc.x, fc.y, fc.z, fc.w};
#pragma unroll
      for (int kx = 0; kx < 5; ++kx) {
        v2f wk = wr[jj * 5 + kx];
#pragma unroll
        for (int j = 0; j < 8; ++j) {
          v2f vv2 = (v2f){f[j + kx], f[j + kx]};
          aA[j] += wk * vv2;
        }
      }
    }
    aA[0] += (v2f){qv0.x, qv0.y}; aA[1] += (v2f){qv0.z, qv0.w};
    aA[2] += (v2f){qv1.x, qv1.y}; aA[3] += (v2f){qv1.z, qv1.w};
    aA[4] += (v2f){qv2.x, qv2.y}; aA[5] += (v2f){qv2.z, qv2.w};
    aA[6] += (v2f){qv3.x, qv3.y}; aA[7] += (v2f){qv3.z, qv3.w};
    // partial projection from this lane's 2 channels, butterfly-sum over cq
    v2f fcp2[4];
#pragma unroll
    for (int a = 0; a < 4; ++a)
      fcp2[a] = (v2f){fc_w[a * 8 + 2 * cq], fc_w[a * 8 + 2 * cq + 1]};
#pragma unroll
    for (int j = 0; j < 8; ++j) {
      float p0 = fcp2[0].x * aA[j].x + fcp2[0].y * aA[j].y;
      float p1 = fcp2[1].x * aA[j].x + fcp2[1].y * aA[j].y;
      float p2 = fcp2[2].x * aA[j].x + fcp2[2].y * aA[j].y;
      float p3 = fcp2[3].x * aA[j].x + fcp2[3].y * aA[j].y;
      p0 += __shfl_xor(p0, 16); p0 += __shfl_xor(p0, 32);
      p1 += __shfl_xor(p1, 16); p1 += __shfl_xor(p1, 32);
      p2 += __shfl_xor(p2, 16); p2 += __shfl_xor(p2, 32);
      p3 += __shfl_xor(p3, 16); p3 += __shfl_xor(p3, 32);
      if (cq == 0)
        *(float4*)&out[((size_t)((b * 64 + r) * 64 + p8 + j)) * 4] =
            make_float4(p0, p1, p2, p3);
    }
  }
}

extern "C" void kernel_launch(void* const* d_in, const int* in_sizes, int n_in,
                              void* d_out, int out_size, void* d_ws, size_t ws_size,
                              hipStream_t stream) {
  const int* maze = (const int*)d_in[0];
  const float* emb = (const float*)d_in[1];
  const float* encode_w = (const float*)d_in[2];
  const float* encode_b = (const float*)d_in[3];
  const float* r_w = (const float*)d_in[4];
  const float* q_w = (const float*)d_in[5];
  const float* w = (const float*)d_in[6];
  const float* fc_w = (const float*)d_in[7];
  float* out = (float*)d_out;

  float* q0g = (float*)d_ws;  // 64*64*4*64*2 floats = 8 MB

  rq_kernel<<<dim3(4, 64), 512, 0, stream>>>(maze, emb, encode_w, encode_b,
                                             r_w, q_w, q0g);
  vi_kernel<<<dim3(4, 64), 1024, 0, stream>>>(q0g, w, fc_w, out);
}

// Round 4
// 115.276 us; speedup vs baseline: 1.0828x; 1.0828x over previous
//
#include <hip/hip_runtime.h>
#include <hip/hip_bf16.h>

// Nav_64939905516231 (VIN value iteration), MI355X gfx950.
// B=64,H=W=64,dim_h=150,n_hat=8,n_act=4,K=10. fp32 in/out, maze int32.
// Collapses: r = conv5x5(m,W_eff)+b_eff (150ch folded); q_t = q0 + conv5x5(v,w).
// R26: fix R25's spill (WRITE_SIZE 29MB = scratch; VGPR=64 meant the ~114-reg
// live set spilled at the 128-reg/4-wave budget). Per-lane work cut 8px->4px:
// lane = (cq = lane>>4 channel pair, p4 = (lane&15)*4). Wave = 1 row x 64 px
// x 8 ch, wave-uniform r (no divergent guard; shfl-safe). Live set ~95 regs
// (50 weights + 8 acc + 8 q0 + 8 taps + misc) -> fits 128 with headroom.
// Per-px-ch FMA/LDS/shfl counts unchanged vs R23/R25. 16 waves, 1 blk/CU,
// 4 waves/SIMD. Tap reads 4-way broadcast across cq groups; 8-ch max via
// shfl_xor(16,32); cq==0 writes combined row. 1 barrier/step, dbuf vbuf.
// ~44us ws-poison fill + ~18us dispatch are harness-fixed.

#define NHAT 8
#define DIMH 150

typedef float v2f __attribute__((ext_vector_type(2)));

// ------- rq: prep (parallel) + r = table-conv(maze) + q0 -------
// q0 layout: q0g[(((b*64+gy)*4 + j)*64 + gx)*2] v2f = ch pair (2j,2j+1).
__global__ __launch_bounds__(512) void rq_kernel(
    const int* __restrict__ maze, const float* __restrict__ emb,
    const float* __restrict__ encode_w, const float* __restrict__ encode_b,
    const float* __restrict__ r_w, const float* __restrict__ q_w,
    float* __restrict__ q0g) {
  __shared__ float wpart[5][50];
  __shared__ float bpart[152];
  __shared__ float weff[2][25];
  __shared__ float Ts[4][25];
  __shared__ float bsh;
  __shared__ v2f qw2[25][4];
  __shared__ unsigned char mzt[24][68];
  __shared__ float rt[20][68];

  int tid = threadIdx.x;
  int b = blockIdx.y, A0 = blockIdx.x * 16;

  // P0: weight stage + W_eff partials + maze tile
  if (tid < 100) {
    int k = tid >> 2, j = tid & 3;
    qw2[k][j] = (v2f){q_w[(2 * j) * 25 + k], q_w[(2 * j + 1) * 25 + k]};
  }
  if (tid >= 256 && tid < 506) {
    int t2 = tid - 256;
    int chunk = t2 / 50, ik = t2 % 50;
    int i = ik / 25, k = ik % 25;
    int c0 = chunk * 30;
    float s = 0.f;
    for (int c = c0; c < c0 + 30; ++c)
      s += r_w[c] * encode_w[c * 50 + i * 25 + k];
    wpart[chunk][ik] = s;
  }
  if (tid >= 100 && tid < 250) {
    int c = tid - 100;
    bpart[c] = r_w[c] * encode_b[c];
  }
  for (int i = tid; i < 24 * 68; i += 512) {
    int mr = i / 68, mc = i % 68;
    int gy = A0 - 4 + mr, gx = mc - 2;
    unsigned char v = 3;
    if (gy >= 0 && gy < 64 && gx >= 0 && gx < 64)
      v = (unsigned char)maze[(b * 64 + gy) * 64 + gx];
    mzt[mr][mc] = v;
  }
  __syncthreads();
  // P1: reduce
  if (tid < 50) {
    float s = 0.f;
#pragma unroll
    for (int ch = 0; ch < 5; ++ch) s += wpart[ch][tid];
    weff[tid / 25][tid % 25] = s;
  }
  if (tid == 50) {
    float s = 0.f;
    for (int c = 0; c < 150; ++c) s += bpart[c];
    bsh = s;
  }
  __syncthreads();
  // P2: T table
  if (tid < 100) {
    int val = tid / 25, k = tid % 25;
    float t = 0.f;
    if (val < 3) t = weff[0][k] * emb[val * 2] + weff[1][k] * emb[val * 2 + 1];
    Ts[val][k] = t;  // row 3 == 0 (padding sentinel)
  }
  __syncthreads();
  // P3: r tile rows [A0-2, A0+18)
  for (int i = tid; i < 20 * 68; i += 512) {
    int rr = i / 68, cc = i % 68;
    int gy = A0 - 2 + rr, gx = cc - 2;
    float v = 0.f;
    if (gy >= 0 && gy < 64 && gx >= 0 && gx < 64) {
      v = bsh;
#pragma unroll
      for (int ky = 0; ky < 5; ++ky)
#pragma unroll
        for (int kx = 0; kx < 5; ++kx)
          v += Ts[mzt[rr + ky][cc - 2 + kx]][ky * 5 + kx];
    }
    rt[rr][cc] = v;
  }
  __syncthreads();
  // P4: q0 on owned 16 rows -> [b][gy][chpair][gx] v2f
  for (int i = tid; i < 16 * 64; i += 512) {
    int ly = i >> 6, gx = i & 63;
    int gy = A0 + ly;
    v2f acc[4];
#pragma unroll
    for (int j = 0; j < 4; ++j) acc[j] = (v2f){0.f, 0.f};
#pragma unroll
    for (int ky = 0; ky < 5; ++ky)
#pragma unroll
      for (int kx = 0; kx < 5; ++kx) {
        int k = ky * 5 + kx;
        float vv = rt[ly + ky][gx + kx];
        v2f vv2 = (v2f){vv, vv};
#pragma unroll
        for (int j = 0; j < 4; ++j) acc[j] += qw2[k][j] * vv2;
      }
#pragma unroll
    for (int j = 0; j < 4; ++j)
      *(v2f*)&q0g[(((size_t)(b * 64 + gy) * 4 + j) * 64 + gx) * 2] = acc[j];
  }
}

// =============== vi: 10 fused VI steps + projection =================
// Block (1024 thr = 16 waves) owns rows [a0, a0+16); grid 256 (1 blk/CU).
// Lane: cq = lane>>4 (channel pair), p4 = (lane&15)*4 (4-px group).
// Wave = 1 row x 64 px x 8 ch, r = s + wave (+16 stride), wave-uniform.
// All 4 cq groups read the SAME vbuf taps (broadcast). 8-ch max via
// shfl_xor(16)+shfl_xor(32); cq==0 writes cols 2+p4..5+p4. 1 barrier/step.
__global__ __launch_bounds__(1024, 4) void vi_kernel(
    const float* __restrict__ q0g, const float* __restrict__ w,
    const float* __restrict__ fc_w, float* __restrict__ out) {
  __shared__ __align__(16) float vbuf[2][60][68];  // 32.6 KB
  __shared__ v2f wl2[25][4];

  int tid = threadIdx.x;
  int b = blockIdx.y, a0 = blockIdx.x * 16;
  int wave = tid >> 6, lane = tid & 63;
  int cq = lane >> 4;        // channel pair 0..3
  int p4 = (lane & 15) * 4;  // px group start

  if (tid < 100) {
    int k = tid >> 2, j = tid & 3;
    wl2[k][j] = (v2f){w[(2 * j) * 25 + k], w[(2 * j + 1) * 25 + k]};
  }
  for (int i = tid; i < 2 * 60 * 68; i += 1024) ((float*)vbuf)[i] = 0.f;
  __syncthreads();

  // this lane's 2 channels -> 25 v2f = 50 regs
  v2f wr[25];
#pragma unroll
  for (int k = 0; k < 25; ++k) wr[k] = wl2[k][cq];

  const float* q0b = q0g + (size_t)b * 64 * 4 * 64 * 2;
  int cur = 0;

  // v0 = max_c q0 on [a0-20, a0+36): full 8ch per lane, waves stride 16 rows
  {
    int s = max(0, a0 - 20), e = min(64, a0 + 36);
    int gx = lane;
    for (int r = s + wave; r < e; r += 16) {
      v2f a0v = *(const v2f*)&q0b[(((size_t)r * 4 + 0) * 64 + gx) * 2];
      v2f a1v = *(const v2f*)&q0b[(((size_t)r * 4 + 1) * 64 + gx) * 2];
      v2f a2v = *(const v2f*)&q0b[(((size_t)r * 4 + 2) * 64 + gx) * 2];
      v2f a3v = *(const v2f*)&q0b[(((size_t)r * 4 + 3) * 64 + gx) * 2];
      float m = fmaxf(fmaxf(fmaxf(a0v.x, a0v.y), fmaxf(a1v.x, a1v.y)),
                      fmaxf(fmaxf(a2v.x, a2v.y), fmaxf(a3v.x, a3v.y)));
      vbuf[0][r - a0 + 22][gx + 2] = m;
    }
  }
  __syncthreads();

  for (int t = 1; t <= 9; ++t) {
    int hh = 2 * (10 - t);
    int s = max(0, a0 - hh), e = min(64, a0 + 16 + hh);
    for (int r = s + wave; r < e; r += 16) {  // wave-uniform row
      int lr = r - a0 + 22;
      const float4* qp =
          (const float4*)&q0b[(((size_t)r * 4 + cq) * 64 + p4) * 2];
      float4 qv0 = qp[0], qv1 = qp[1];
      v2f aA[4];
#pragma unroll
      for (int j = 0; j < 4; ++j) aA[j] = (v2f){0.f, 0.f};
#pragma unroll
      for (int jj = 0; jj < 5; ++jj) {
        const float* row = &vbuf[cur][lr - 2 + jj][p4];
        float4 fa = *(const float4*)row;
        float4 fb = *(const float4*)(row + 4);
        float f[8] = {fa.x, fa.y, fa.z, fa.w, fb.x, fb.y, fb.z, fb.w};
#pragma unroll
        for (int kx = 0; kx < 5; ++kx) {
          v2f wk = wr[jj * 5 + kx];
#pragma unroll
          for (int j = 0; j < 4; ++j) {
            v2f vv2 = (v2f){f[j + kx], f[j + kx]};
            aA[j] += wk * vv2;
          }
        }
      }
      // q0 added after the tap chain: L2 latency hides under FMAs
      aA[0] += (v2f){qv0.x, qv0.y};
      aA[1] += (v2f){qv0.z, qv0.w};
      aA[2] += (v2f){qv1.x, qv1.y};
      aA[3] += (v2f){qv1.z, qv1.w};
      float m0 = fmaxf(aA[0].x, aA[0].y), m1 = fmaxf(aA[1].x, aA[1].y);
      float m2 = fmaxf(aA[2].x, aA[2].y), m3 = fmaxf(aA[3].x, aA[3].y);
      // combine the 4 channel pairs in-register (butterfly over cq)
      m0 = fmaxf(m0, __shfl_xor(m0, 16)); m0 = fmaxf(m0, __shfl_xor(m0, 32));
      m1 = fmaxf(m1, __shfl_xor(m1, 16)); m1 = fmaxf(m1, __shfl_xor(m1, 32));
      m2 = fmaxf(m2, __shfl_xor(m2, 16)); m2 = fmaxf(m2, __shfl_xor(m2, 32));
      m3 = fmaxf(m3, __shfl_xor(m3, 16)); m3 = fmaxf(m3, __shfl_xor(m3, 32));
      if (cq == 0) {
        // pixels p4+0..p4+3 -> cols 2+p4 .. 5+p4 (8B-aligned v2f stores)
        *(v2f*)&vbuf[cur ^ 1][lr][2 + p4] = (v2f){m0, m1};
        *(v2f*)&vbuf[cur ^ 1][lr][4 + p4] = (v2f){m2, m3};
      }
    }
    __syncthreads();
    cur ^= 1;
  }

  // final step t=10 + projection: wave owns row a0+wave
  {
    int r = a0 + wave;
    int lr = r - a0 + 22;
    const float4* qp =
        (const float4*)&q0b[(((size_t)r * 4 + cq) * 64 + p4) * 2];
    float4 qv0 = qp[0], qv1 = qp[1];
    v2f aA[4];
#pragma unroll
    for (int j = 0; j < 4; ++j) aA[j] = (v2f){0.f, 0.f};
#pragma unroll
    for (int jj = 0; jj < 5; ++jj) {
      const float* row = &vbuf[cur][lr - 2 + jj][p4];
      float4 fa = *(const float4*)row;
      float4 fb = *(const float4*)(row + 4);
      float f[8] = {fa.x, fa.y, fa.z, fa.w, fb.x, fb.y, fb.z, fb.w};
#pragma unroll
      for (int kx = 0; kx < 5; ++kx) {
        v2f wk = wr[jj * 5 + kx];
#pragma unroll
        for (int j = 0; j < 4; ++j) {
          v2f vv2 = (v2f){f[j + kx], f[j + kx]};
          aA[j] += wk * vv2;
        }
      }
    }
    aA[0] += (v2f){qv0.x, qv0.y};
    aA[1] += (v2f){qv0.z, qv0.w};
    aA[2] += (v2f){qv1.x, qv1.y};
    aA[3] += (v2f){qv1.z, qv1.w};
    // partial projection from this lane's 2 channels, butterfly-sum over cq
    v2f fcp2[4];
#pragma unroll
    for (int a = 0; a < 4; ++a)
      fcp2[a] = (v2f){fc_w[a * 8 + 2 * cq], fc_w[a * 8 + 2 * cq + 1]};
#pragma unroll
    for (int j = 0; j < 4; ++j) {
      float p0 = fcp2[0].x * aA[j].x + fcp2[0].y * aA[j].y;
      float p1 = fcp2[1].x * aA[j].x + fcp2[1].y * aA[j].y;
      float p2 = fcp2[2].x * aA[j].x + fcp2[2].y * aA[j].y;
      float p3 = fcp2[3].x * aA[j].x + fcp2[3].y * aA[j].y;
      p0 += __shfl_xor(p0, 16); p0 += __shfl_xor(p0, 32);
      p1 += __shfl_xor(p1, 16); p1 += __shfl_xor(p1, 32);
      p2 += __shfl_xor(p2, 16); p2 += __shfl_xor(p2, 32);
      p3 += __shfl_xor(p3, 16); p3 += __shfl_xor(p3, 32);
      if (cq == 0)
        *(float4*)&out[((size_t)((b * 64 + r) * 64 + p4 + j)) * 4] =
            make_float4(p0, p1, p2, p3);
    }
  }
}

extern "C" void kernel_launch(void* const* d_in, const int* in_sizes, int n_in,
                              void* d_out, int out_size, void* d_ws, size_t ws_size,
                              hipStream_t stream) {
  const int* maze = (const int*)d_in[0];
  const float* emb = (const float*)d_in[1];
  const float* encode_w = (const float*)d_in[2];
  const float* encode_b = (const float*)d_in[3];
  const float* r_w = (const float*)d_in[4];
  const float* q_w = (const float*)d_in[5];
  const float* w = (const float*)d_in[6];
  const float* fc_w = (const float*)d_in[7];
  float* out = (float*)d_out;

  float* q0g = (float*)d_ws;  // 64*64*4*64*2 floats = 8 MB

  rq_kernel<<<dim3(4, 64), 512, 0, stream>>>(maze, emb, encode_w, encode_b,
                                             r_w, q_w, q0g);
  vi_kernel<<<dim3(4, 64), 1024, 0, stream>>>(q0g, w, fc_w, out);
}